// Round 5
// baseline (160.174 us; speedup 1.0000x reference)
//
#include <hip/hip_runtime.h>
#include <hip/hip_fp16.h>

// MinibatchDiscrimination  B=256, IN_F=1024, OUT_F=128, KD=16 (fp32 in/out)
// out[b] = concat(x[b], o_b[b]); o_b[b][o] = sum_b2 exp(-L1(m[b,o,:], m[b2,o,:])) - 1
//
// R5: SINGLE fused kernel. Dispatch_Id arithmetic (fills always == 4 mod 7 in
// R2-R4) proved 7 nodes/iter with ~7.4 us/node gap -> node count is the
// bottleneck, not exec. Block (o, h): redundantly computes m[:, o-slice]
// (M=256,N=16,K=1024) via LDS-staged bf16 MFMA (m stays in LDS, never global),
// then pairwise for its b1-half. No cross-block deps, no atomics, no ws use.
// Numerics (R1-R4, absmax=0.0): cross-pair norms ~580 -> expf underflows to
// exact 0; self-pair diff is bitwise 0 (my and ot read the same LDS row).

#define BATCH 256
#define INF   1024
#define OUTF  128
#define KDIM  16
#define TCOLS 2048
#define OCOLS 1152

typedef __attribute__((ext_vector_type(8))) short short8;
typedef __attribute__((ext_vector_type(4))) float f32x4;

__device__ inline unsigned short bf_trunc(float f) {
    return (unsigned short)(__float_as_uint(f) >> 16);
}
// pack two fp32 -> two bf16 (trunc) in one v_perm: low16 = lo, high16 = hi
__device__ inline unsigned pack_bf2(float lo, float hi) {
    return __builtin_amdgcn_perm(__float_as_uint(hi), __float_as_uint(lo), 0x07060302u);
}

// LDS layout (aliased regions):
//   phase A (gemm):    xs[256][72] bf16 (36864 B) | bs[16][72] bf16 (2304 B)
//   phase B (pairwise): pm[256][8] half2 (8192 B) | part[256] f32 (1024 B)
// row pad 72 (144 B = 9x16B): keeps ds_read_b128 16B-aligned, banks spread.
#define XROW 72
#define LDS_BYTES (256 * XROW * 2 + 16 * XROW * 2)

__global__ __launch_bounds__(256) void k_fused(const float* __restrict__ x,
                                               const float* __restrict__ T,
                                               float* __restrict__ out) {
    const int blk = blockIdx.x;          // 256 blocks
    const int o   = blk & 127;           // output channel
    const int h   = blk >> 7;            // b1 half
    const int tid = threadIdx.x;
    const int wave = tid >> 6, lane = tid & 63;
    const int l15 = lane & 15, q = lane >> 4;

    __shared__ __align__(16) char Lraw[LDS_BYTES];
    unsigned short (*xs)[XROW] = reinterpret_cast<unsigned short (*)[XROW]>(Lraw);
    unsigned short (*bs)[XROW] = reinterpret_cast<unsigned short (*)[XROW]>(Lraw + 256 * XROW * 2);
    __half2 (*pm)[8] = reinterpret_cast<__half2 (*)[8]>(Lraw);            // aliases xs
    float* part      = reinterpret_cast<float*>(Lraw + 256 * 8 * 4);      // after pm

    // ---- fold-in: out x-copy (block blk copies x row blk; 256 thr x float4)
    {
        float4 v = reinterpret_cast<const float4*>(x)[blk * 256 + tid];
        reinterpret_cast<float4*>(out)[blk * 288 + tid] = v;
    }

    // ---- phase A: m[256][16] = x @ T[:, o*16 .. o*16+16), bf16 MFMA, 16 k-slabs
    f32x4 acc[4] = {{0,0,0,0},{0,0,0,0},{0,0,0,0},{0,0,0,0}};
    const int rbase = tid >> 4;          // staging row group
    const int col4  = (tid & 15) * 4;    // staging k offset (floats)
    const int bk    = tid >> 2;          // B staging k (0..63)
    const int bn4   = (tid & 3) * 4;     // B staging n group

    #pragma unroll 1
    for (int s = 0; s < 16; ++s) {
        __syncthreads();                 // LDS reuse guard
        // stage x slab [256 rows][64 k] fp32 -> bf16 (coalesced: 16 thr/row-seg)
        #pragma unroll
        for (int p = 0; p < 16; ++p) {
            const int row = p * 16 + rbase;
            float4 v = *reinterpret_cast<const float4*>(&x[row * INF + s * 64 + col4]);
            *reinterpret_cast<uint2*>(&xs[row][col4]) =
                make_uint2(pack_bf2(v.x, v.y), pack_bf2(v.z, v.w));
        }
        // stage B slab: T[s*64+k][o*16 + n] -> bs[n][k] (transposed, bf16)
        {
            float4 v = *reinterpret_cast<const float4*>(&T[(s * 64 + bk) * TCOLS + o * KDIM + bn4]);
            bs[bn4 + 0][bk] = bf_trunc(v.x);
            bs[bn4 + 1][bk] = bf_trunc(v.y);
            bs[bn4 + 2][bk] = bf_trunc(v.z);
            bs[bn4 + 3][bk] = bf_trunc(v.w);
        }
        __syncthreads();
        // MFMA: wave w owns m-tiles w*4..w*4+3; 2 k-steps of 32 per slab
        #pragma unroll
        for (int kk = 0; kk < 2; ++kk) {
            short8 b = *reinterpret_cast<const short8*>(&bs[l15][kk * 32 + q * 8]);
            #pragma unroll
            for (int mtl = 0; mtl < 4; ++mtl) {
                short8 a = *reinterpret_cast<const short8*>(
                    &xs[(wave * 4 + mtl) * 16 + l15][kk * 32 + q * 8]);
                acc[mtl] = __builtin_amdgcn_mfma_f32_16x16x32_bf16(a, b, acc[mtl], 0, 0, 0);
            }
        }
    }
    __syncthreads();   // drain last frag reads before aliasing xs -> pm

    // ---- write m to LDS as fp16: D layout col=l15 (=n), row=q*4+r (m89/m91)
    #pragma unroll
    for (int mtl = 0; mtl < 4; ++mtl) {
        const int row0 = (wave * 4 + mtl) * 16 + q * 4;
        #pragma unroll
        for (int r = 0; r < 4; ++r)
            reinterpret_cast<__half*>(&pm[row0 + r][0])[l15] = __float2half(acc[mtl][r]);
    }
    __syncthreads();

    // ---- phase B: pairwise. thread t: b1 = h*128 + (t&127), b2-half = t>>7.
    const int i1   = tid & 127;
    const int b1   = h * 128 + i1;
    const int bsel = tid >> 7;
    __half2 my[8];
    {
        union { uint4 u[2]; __half2 hh[8]; } c;
        c.u[0] = *reinterpret_cast<const uint4*>(&pm[b1][0]);
        c.u[1] = *reinterpret_cast<const uint4*>(&pm[b1][4]);
        #pragma unroll
        for (int j = 0; j < 8; ++j) my[j] = c.hh[j];
    }
    float tot = 0.f;
    const int b2_lo = bsel * 128;
    #pragma unroll 2
    for (int b2 = b2_lo; b2 < b2_lo + 128; ++b2) {
        union { uint4 u[2]; __half2 hh[8]; } co;        // wave-uniform -> broadcast
        co.u[0] = *reinterpret_cast<const uint4*>(&pm[b2][0]);
        co.u[1] = *reinterpret_cast<const uint4*>(&pm[b2][4]);
        __half2 e0 = __float2half2_rn(0.f), e1 = __float2half2_rn(0.f);
        __half2 e2 = __float2half2_rn(0.f), e3 = __float2half2_rn(0.f);
        #pragma unroll
        for (int j = 0; j < 2; ++j) {
            e0 = __hadd2(e0, __habs2(__hsub2(my[j],     co.hh[j])));
            e1 = __hadd2(e1, __habs2(__hsub2(my[j + 2], co.hh[j + 2])));
            e2 = __hadd2(e2, __habs2(__hsub2(my[j + 4], co.hh[j + 4])));
            e3 = __hadd2(e3, __habs2(__hsub2(my[j + 6], co.hh[j + 6])));
        }
        __half2 es = __hadd2(__hadd2(e0, e1), __hadd2(e2, e3));
        float n = __low2float(es) + __high2float(es);
        tot += __expf(-n);     // b2==b1: same LDS row -> diff bitwise 0 -> +1 exactly
    }
    part[bsel * 128 + i1] = tot;
    __syncthreads();

    // combine two b2-halves; -1 removes the self-pair. Each (b1,o) written once.
    if (tid < 128)
        out[(h * 128 + tid) * OCOLS + INF + o] = part[tid] + part[128 + tid] - 1.0f;
}

// ---------------------------------------------------------------- launch
extern "C" void kernel_launch(void* const* d_in, const int* in_sizes, int n_in,
                              void* d_out, int out_size, void* d_ws, size_t ws_size,
                              hipStream_t stream) {
    const float* x = (const float*)d_in[0];   // [256][1024]
    const float* T = (const float*)d_in[1];   // [1024][2048]
    float* out = (float*)d_out;               // [256][1152]
    (void)d_ws; (void)ws_size;                // no scratch needed anymore

    k_fused<<<256, 256, 0, stream>>>(x, T, out);
}

// Round 6
// 100.539 us; speedup vs baseline: 1.5932x; 1.5932x over previous
//
#include <hip/hip_runtime.h>
#include <hip/hip_fp16.h>

// MinibatchDiscrimination  B=256, IN_F=1024, OUT_F=128, KD=16 (fp32 in/out)
// out[b] = concat(x[b], o_b[b]); o_b[b][o] = sum_b2 exp(-L1(m[b,o,:], m[b2,o,:])) - 1
//
// R6: single fused kernel, latency-tolerant reshape of R5 (which ran 104 us at
// 11% occupancy / 8% VALUBusy: 1 wave/SIMD + 32 barrier-separated staging slabs
// = exposed global latency; session law: <2 waves/SIMD with latency chains
// always lands 55-105 us). Changes:
//   (a) 512 thr/block -> 8 waves/CU (2/SIMD);
//   (b) T-slice staged to LDS ONCE (bf16, padded rows), barrier count in GEMM
//       main loop = 0: A-frags load straight from global x (dwordx4, in-register
//       v_perm fp32->bf16), unroll-4 -> ~16 loads in flight;
//   (c) pairwise: 128 b1-lanes x 4 b2-quarters, pm[b2] reads wave-uniform.
// Cost model: x re-read 256 blocks x 1 MB = 256 MB L2 ~7.4 us + pairwise VALU
// ~3.2 us + staging ~1 us => ~12-15 us exec.
// Numerics (R1-R5, absmax=0.0): cross-pair norms ~580 -> expf underflows to
// exact 0; self-pair diff bitwise 0 (same LDS row) -> +1 exactly, -1 at end.

#define BATCH 256
#define INF   1024
#define OUTF  128
#define KDIM  16
#define TCOLS 2048
#define OCOLS 1152
#define XB    1032   // bs row length in bf16 elems: 2064 B = 129*16 -> 16B-aligned,
                     // row start bank advances 4/row -> frag reads <=2-way (free, m136)

typedef __attribute__((ext_vector_type(8))) short short8;
typedef __attribute__((ext_vector_type(4))) float f32x4;

// pack two fp32 -> two bf16 (trunc) in one v_perm: low16 = lo, high16 = hi
__device__ inline unsigned pack_bf2(float lo, float hi) {
    return __builtin_amdgcn_perm(__float_as_uint(hi), __float_as_uint(lo), 0x07060302u);
}
__device__ inline unsigned short bf_trunc(float f) {
    return (unsigned short)(__float_as_uint(f) >> 16);
}

// LDS: bs[16][XB] bf16 = 33,024 B (phase A); aliased after barrier:
//   pm[256][8] half2 = 8192 B  |  part[512] f32 = 2048 B  (disjoint: part at +8192)
#define LDS_BYTES (16 * XB * 2)

__global__ __launch_bounds__(512) void k_fused(const float* __restrict__ x,
                                               const float* __restrict__ T,
                                               float* __restrict__ out) {
    const int blk = blockIdx.x;           // 256 blocks = (o, h)
    const int o   = blk & 127;
    const int h   = blk >> 7;
    const int tid = threadIdx.x;          // 512 = 8 waves
    const int wave = tid >> 6, lane = tid & 63;
    const int l15 = lane & 15, q = lane >> 4;

    __shared__ __align__(16) char Lraw[LDS_BYTES];
    unsigned short (*bs)[XB] = reinterpret_cast<unsigned short (*)[XB]>(Lraw);
    __half2 (*pm)[8] = reinterpret_cast<__half2 (*)[8]>(Lraw);       // aliases bs
    float* part      = reinterpret_cast<float*>(Lraw + 8192);        // after pm

    // ---- prologue: copy x row blk into out (cols 0..1023); tail written in epilogue
    if (tid < 256)
        reinterpret_cast<float4*>(out)[blk * 288 + tid] =
            reinterpret_cast<const float4*>(x)[blk * 256 + tid];

    // ---- stage T-slice: bs[n][k] = bf16(T[k][o*16+n]), k=0..1023, n=0..15
    // 8 passes x (4 threads per k-row, one float4 each). One barrier total.
    {
        const int kb = tid >> 2, n0 = (tid & 3) * 4;
        #pragma unroll
        for (int pass = 0; pass < 8; ++pass) {
            const int k = pass * 128 + kb;
            float4 v = *reinterpret_cast<const float4*>(&T[k * TCOLS + o * KDIM + n0]);
            bs[n0 + 0][k] = bf_trunc(v.x);
            bs[n0 + 1][k] = bf_trunc(v.y);
            bs[n0 + 2][k] = bf_trunc(v.z);
            bs[n0 + 3][k] = bf_trunc(v.w);
        }
    }
    __syncthreads();

    // ---- GEMM: wave w owns m-tiles 2w, 2w+1 (rows w*32 + {0,16} + l15).
    // Zero barriers: B-frag from LDS (reused across both tiles), A-frags from
    // global x with in-register fp32->bf16. 32 k-steps of 32.
    f32x4 acc0 = {0.f, 0.f, 0.f, 0.f}, acc1 = {0.f, 0.f, 0.f, 0.f};
    const float* xr0 = &x[(wave * 32 + l15) * INF + q * 8];
    const float* xr1 = xr0 + 16 * INF;
    #pragma unroll 4
    for (int ks = 0; ks < 32; ++ks) {
        const int k0 = ks * 32;
        short8 bfr = *reinterpret_cast<const short8*>(&bs[l15][k0 + q * 8]);
        float4 a0 = *reinterpret_cast<const float4*>(xr0 + k0);
        float4 a1 = *reinterpret_cast<const float4*>(xr0 + k0 + 4);
        float4 c0 = *reinterpret_cast<const float4*>(xr1 + k0);
        float4 c1 = *reinterpret_cast<const float4*>(xr1 + k0 + 4);
        union { unsigned u[4]; short8 s; } ua, uc;
        ua.u[0] = pack_bf2(a0.x, a0.y); ua.u[1] = pack_bf2(a0.z, a0.w);
        ua.u[2] = pack_bf2(a1.x, a1.y); ua.u[3] = pack_bf2(a1.z, a1.w);
        uc.u[0] = pack_bf2(c0.x, c0.y); uc.u[1] = pack_bf2(c0.z, c0.w);
        uc.u[2] = pack_bf2(c1.x, c1.y); uc.u[3] = pack_bf2(c1.z, c1.w);
        acc0 = __builtin_amdgcn_mfma_f32_16x16x32_bf16(ua.s, bfr, acc0, 0, 0, 0);
        acc1 = __builtin_amdgcn_mfma_f32_16x16x32_bf16(uc.s, bfr, acc1, 0, 0, 0);
    }
    __syncthreads();   // all bs reads done before aliasing onto pm

    // ---- write m-slice to LDS fp16. D layout: col(n)=l15, row=q*4+r (m89/m91).
    {
        const int row0 = wave * 32 + q * 4;
        #pragma unroll
        for (int r = 0; r < 4; ++r)
            reinterpret_cast<__half*>(&pm[row0 + r][0])[l15] = __float2half(acc0[r]);
        #pragma unroll
        for (int r = 0; r < 4; ++r)
            reinterpret_cast<__half*>(&pm[row0 + 16 + r][0])[l15] = __float2half(acc1[r]);
    }
    __syncthreads();

    // ---- pairwise: thread = (i1 = tid&127 -> b1 = h*128+i1, bsel = tid>>7).
    // b2 in [bsel*64, bsel*64+64); pm[b2] wave-uniform -> LDS broadcast.
    const int i1 = tid & 127;
    const int b1 = h * 128 + i1;
    const int bsel = tid >> 7;
    __half2 my[8];
    {
        union { uint4 u[2]; __half2 hh[8]; } c;
        c.u[0] = *reinterpret_cast<const uint4*>(&pm[b1][0]);
        c.u[1] = *reinterpret_cast<const uint4*>(&pm[b1][4]);
        #pragma unroll
        for (int j = 0; j < 8; ++j) my[j] = c.hh[j];
    }
    float tot = 0.f;
    const int b2_lo = bsel * 64;
    #pragma unroll 2
    for (int b2 = b2_lo; b2 < b2_lo + 64; ++b2) {
        union { uint4 u[2]; __half2 hh[8]; } co;
        co.u[0] = *reinterpret_cast<const uint4*>(&pm[b2][0]);
        co.u[1] = *reinterpret_cast<const uint4*>(&pm[b2][4]);
        __half2 e0 = __float2half2_rn(0.f), e1 = __float2half2_rn(0.f);
        __half2 e2 = __float2half2_rn(0.f), e3 = __float2half2_rn(0.f);
        #pragma unroll
        for (int j = 0; j < 2; ++j) {
            e0 = __hadd2(e0, __habs2(__hsub2(my[j],     co.hh[j])));
            e1 = __hadd2(e1, __habs2(__hsub2(my[j + 2], co.hh[j + 2])));
            e2 = __hadd2(e2, __habs2(__hsub2(my[j + 4], co.hh[j + 4])));
            e3 = __hadd2(e3, __habs2(__hsub2(my[j + 6], co.hh[j + 6])));
        }
        __half2 es = __hadd2(__hadd2(e0, e1), __hadd2(e2, e3));
        float n = __low2float(es) + __high2float(es);
        tot += __expf(-n);     // b2==b1: same LDS row -> diff bitwise 0 -> +1 exactly
    }
    part[bsel * 128 + i1] = tot;
    __syncthreads();

    // ---- epilogue: combine 4 b2-quarters; -1 removes self-pair. One writer per (b,o).
    if (tid < 128)
        out[(h * 128 + tid) * OCOLS + INF + o] =
            part[tid] + part[128 + tid] + part[256 + tid] + part[384 + tid] - 1.0f;
}

// ---------------------------------------------------------------- launch
extern "C" void kernel_launch(void* const* d_in, const int* in_sizes, int n_in,
                              void* d_out, int out_size, void* d_ws, size_t ws_size,
                              hipStream_t stream) {
    const float* x = (const float*)d_in[0];   // [256][1024]
    const float* T = (const float*)d_in[1];   // [1024][2048]
    float* out = (float*)d_out;               // [256][1152]
    (void)d_ws; (void)ws_size;

    k_fused<<<256, 512, 0, stream>>>(x, T, out);
}

// Round 7
// 100.353 us; speedup vs baseline: 1.5961x; 1.0019x over previous
//
#include <hip/hip_runtime.h>
#include <hip/hip_fp16.h>

// MinibatchDiscrimination  B=256, IN_F=1024, OUT_F=128, KD=16 (fp32 in/out)
// out[b] = concat(x[b], o_b[b]); o_b[b][o] = sum_b2 exp(-L1(m[b,o,:], m[b2,o,:])) - 1
//
// R7: R6 structure, 1024 thr/block (16 waves/CU = 4/SIMD). Session law
// (R5->R6: waves 4->8/CU, time 104->45.5 us, HBM 4%, VALU 17%): this kernel is
// purely latency-bound and scales ~linearly with TLP. One more doubling.
//   - wave w owns m-tile w (16 rows): zero-barrier GEMM, A-frags straight from
//     global x (dwordx4 + in-register v_perm fp32->bf16), B-frag from LDS.
//   - pairwise: 128 b1-lanes x 8 b2-eighths, unroll 4 (more ds_reads in flight).
//   - epilogue: 8-way partial combine, one writer per (b,o).
// Numerics (R1-R6, absmax=0.0): cross-pair norms ~580 -> expf underflows to
// exact 0; self-pair diff bitwise 0 (same LDS row) -> +1 exactly, -1 at end.

#define BATCH 256
#define INF   1024
#define OUTF  128
#define KDIM  16
#define TCOLS 2048
#define OCOLS 1152
#define XB    1032   // bs row = 2064 B = 129*16: 16B-aligned, bank shift 4/row,
                     // b128 frag reads <=2-way aliased = free (m136)

typedef __attribute__((ext_vector_type(8))) short short8;
typedef __attribute__((ext_vector_type(4))) float f32x4;

// pack two fp32 -> two bf16 (trunc) in one v_perm: low16 = lo, high16 = hi
__device__ inline unsigned pack_bf2(float lo, float hi) {
    return __builtin_amdgcn_perm(__float_as_uint(hi), __float_as_uint(lo), 0x07060302u);
}
__device__ inline unsigned short bf_trunc(float f) {
    return (unsigned short)(__float_as_uint(f) >> 16);
}

// LDS: phase A: bs[16][XB] bf16 = 33,024 B. Phase B aliases onto it:
//   pm[256][8] half2 = 8192 B | part[8*128] f32 = 4096 B (at +8192)
#define LDS_BYTES (16 * XB * 2)

__global__ __launch_bounds__(1024) void k_fused(const float* __restrict__ x,
                                                const float* __restrict__ T,
                                                float* __restrict__ out) {
    const int blk = blockIdx.x;           // 256 blocks = (o, h)
    const int o   = blk & 127;
    const int h   = blk >> 7;
    const int tid = threadIdx.x;          // 1024 = 16 waves
    const int wave = tid >> 6, lane = tid & 63;
    const int l15 = lane & 15, q = lane >> 4;

    __shared__ __align__(16) char Lraw[LDS_BYTES];
    unsigned short (*bs)[XB] = reinterpret_cast<unsigned short (*)[XB]>(Lraw);
    __half2 (*pm)[8] = reinterpret_cast<__half2 (*)[8]>(Lraw);       // aliases bs
    float* part      = reinterpret_cast<float*>(Lraw + 8192);        // after pm

    // ---- prologue: copy x row blk into out (cols 0..1023)
    if (tid < 256)
        reinterpret_cast<float4*>(out)[blk * 288 + tid] =
            reinterpret_cast<const float4*>(x)[blk * 256 + tid];

    // ---- stage T-slice: bs[n][k] = bf16(T[k][o*16+n]); 4 passes x 256 k-rows
    {
        const int kb = tid >> 2, n0 = (tid & 3) * 4;
        #pragma unroll
        for (int pass = 0; pass < 4; ++pass) {
            const int k = pass * 256 + kb;
            float4 v = *reinterpret_cast<const float4*>(&T[k * TCOLS + o * KDIM + n0]);
            bs[n0 + 0][k] = bf_trunc(v.x);
            bs[n0 + 1][k] = bf_trunc(v.y);
            bs[n0 + 2][k] = bf_trunc(v.z);
            bs[n0 + 3][k] = bf_trunc(v.w);
        }
    }
    __syncthreads();

    // ---- GEMM: wave w owns m-tile w (rows w*16 + l15). Zero barriers inside:
    // B-frag from LDS, A-frag from global x with in-register fp32->bf16.
    f32x4 acc = {0.f, 0.f, 0.f, 0.f};
    const float* xr = &x[(wave * 16 + l15) * INF + q * 8];
    #pragma unroll 4
    for (int ks = 0; ks < 32; ++ks) {
        const int k0 = ks * 32;
        short8 bfr = *reinterpret_cast<const short8*>(&bs[l15][k0 + q * 8]);
        float4 a0 = *reinterpret_cast<const float4*>(xr + k0);
        float4 a1 = *reinterpret_cast<const float4*>(xr + k0 + 4);
        union { unsigned u[4]; short8 s; } ua;
        ua.u[0] = pack_bf2(a0.x, a0.y); ua.u[1] = pack_bf2(a0.z, a0.w);
        ua.u[2] = pack_bf2(a1.x, a1.y); ua.u[3] = pack_bf2(a1.z, a1.w);
        acc = __builtin_amdgcn_mfma_f32_16x16x32_bf16(ua.s, bfr, acc, 0, 0, 0);
    }
    __syncthreads();   // all bs reads done before aliasing onto pm

    // ---- write m-slice to LDS fp16. D layout: col(n)=l15, row=q*4+r (m89/m91).
    {
        const int row0 = wave * 16 + q * 4;
        #pragma unroll
        for (int r = 0; r < 4; ++r)
            reinterpret_cast<__half*>(&pm[row0 + r][0])[l15] = __float2half(acc[r]);
    }
    __syncthreads();

    // ---- pairwise: i1 = tid&127 -> b1 = h*128+i1; bsel = tid>>7 (0..7);
    // b2 in [bsel*32, bsel*32+32). pm[b2] wave-uniform -> LDS broadcast.
    const int i1 = tid & 127;
    const int b1 = h * 128 + i1;
    const int bsel = tid >> 7;
    __half2 my[8];
    {
        union { uint4 u[2]; __half2 hh[8]; } c;
        c.u[0] = *reinterpret_cast<const uint4*>(&pm[b1][0]);
        c.u[1] = *reinterpret_cast<const uint4*>(&pm[b1][4]);
        #pragma unroll
        for (int j = 0; j < 8; ++j) my[j] = c.hh[j];
    }
    float tot = 0.f;
    const int b2_lo = bsel * 32;
    #pragma unroll 4
    for (int b2 = b2_lo; b2 < b2_lo + 32; ++b2) {
        union { uint4 u[2]; __half2 hh[8]; } co;
        co.u[0] = *reinterpret_cast<const uint4*>(&pm[b2][0]);
        co.u[1] = *reinterpret_cast<const uint4*>(&pm[b2][4]);
        __half2 e0 = __float2half2_rn(0.f), e1 = __float2half2_rn(0.f);
        __half2 e2 = __float2half2_rn(0.f), e3 = __float2half2_rn(0.f);
        #pragma unroll
        for (int j = 0; j < 2; ++j) {
            e0 = __hadd2(e0, __habs2(__hsub2(my[j],     co.hh[j])));
            e1 = __hadd2(e1, __habs2(__hsub2(my[j + 2], co.hh[j + 2])));
            e2 = __hadd2(e2, __habs2(__hsub2(my[j + 4], co.hh[j + 4])));
            e3 = __hadd2(e3, __habs2(__hsub2(my[j + 6], co.hh[j + 6])));
        }
        __half2 es = __hadd2(__hadd2(e0, e1), __hadd2(e2, e3));
        float n = __low2float(es) + __high2float(es);
        tot += __expf(-n);     // b2==b1: same LDS row -> diff bitwise 0 -> +1 exactly
    }
    part[bsel * 128 + i1] = tot;
    __syncthreads();

    // ---- epilogue: combine 8 b2-eighths; -1 removes self-pair.
    if (tid < 128) {
        float s = -1.0f;
        #pragma unroll
        for (int j = 0; j < 8; ++j) s += part[j * 128 + tid];
        out[(h * 128 + tid) * OCOLS + INF + o] = s;
    }
}

// ---------------------------------------------------------------- launch
extern "C" void kernel_launch(void* const* d_in, const int* in_sizes, int n_in,
                              void* d_out, int out_size, void* d_ws, size_t ws_size,
                              hipStream_t stream) {
    const float* x = (const float*)d_in[0];   // [256][1024]
    const float* T = (const float*)d_in[1];   // [1024][2048]
    float* out = (float*)d_out;               // [256][1152]
    (void)d_ws; (void)ws_size;

    k_fused<<<256, 1024, 0, stream>>>(x, T, out);
}

// Round 8
// 88.530 us; speedup vs baseline: 1.8093x; 1.1335x over previous
//
#include <hip/hip_runtime.h>
#include <hip/hip_fp16.h>

// MinibatchDiscrimination  B=256, IN_F=1024, OUT_F=128, KD=16 (fp32 in/out)
// out[b] = concat(x[b], o_b[b]); o_b[b][o] = sum_b2 exp(-L1(m[b,o,:], m[b2,o,:])) - 1
//
// R8: split R7's fused kernel into k_gemm + k_pair (+1 node = +2.2 us, measured
// R5/R7: 1-kernel fixed cost 55.3 us, 2.2 us/extra node).
//  - R6==R7 (45.5 vs 45.1 us) despite 2x occupancy: fused kernel saturates at
//    ~45 us; phases can't be decomposed in one dispatch. Split = measurement.
//  - k_gemm computes each 16x16 m-tile ONCE (R7's h-split duplicated all of
//    phase A): half the MFMA work, half the 256-MB L2 x-traffic. Writes mh in
//    pairwise-native layout [o][b][kd] fp16 (1 MB ws) via LDS repack ->
//    coalesced uint4 stores; k_pair reads its slice as one contiguous 8 KB.
//  - k_pair = R7 phase-B verbatim + x-copy prologue.
// Numerics (R1-R7, absmax=0.0): cross-pair norms ~580 -> expf underflows to
// exact 0; self-pair diff bitwise 0 (same LDS rows) -> +1 exactly, -1 at end.

#define BATCH 256
#define INF   1024
#define OUTF  128
#define KDIM  16
#define TCOLS 2048
#define OCOLS 1152
#define XB    1032   // bs row = 2064 B = 129*16: 16B-aligned, bank shift 4/row,
                     // b128 frag reads <=2-way aliased = free (m136)

typedef __attribute__((ext_vector_type(8))) short short8;
typedef __attribute__((ext_vector_type(4))) float f32x4;

// pack two fp32 -> two bf16 (trunc) in one v_perm: low16 = lo, high16 = hi
__device__ inline unsigned pack_bf2(float lo, float hi) {
    return __builtin_amdgcn_perm(__float_as_uint(hi), __float_as_uint(lo), 0x07060302u);
}
__device__ inline unsigned short bf_trunc(float f) {
    return (unsigned short)(__float_as_uint(f) >> 16);
}

// ---------------------------------------------------------------- k_gemm
// Block = (o 0..127, mq 0..3), 256 thr = 4 waves; wave w -> m-tile mq*4+w
// (16 rows). B-slice (T cols o*16..o*16+16, all k) staged once to LDS bf16;
// zero-barrier K-loop: A-frags from global x fp32 with in-register cvt.
// Epilogue: acc -> LDS repack -> coalesced mh[o][mq*64..+64][0..16) fp16.
// 512 blocks x 4 waves = 2048 waves = 8 waves/CU.
__global__ __launch_bounds__(256) void k_gemm(const float* __restrict__ x,
                                              const float* __restrict__ T,
                                              __half* __restrict__ mh) {
    const int blk = blockIdx.x;
    const int o   = blk & 127;
    const int mq  = blk >> 7;
    const int tid = threadIdx.x;
    const int wave = tid >> 6, lane = tid & 63;
    const int l15 = lane & 15, q = lane >> 4;

    __shared__ unsigned short bs[16][XB];   // 33,024 B
    __shared__ __half pmout[64][16];        //  2,048 B (separate region, no alias)

    // stage B: bs[n][k] = bf16(T[k][o*16+n]); 16 passes x 64 k-rows
    {
        const int kb = tid >> 2, n0 = (tid & 3) * 4;
        #pragma unroll
        for (int pass = 0; pass < 16; ++pass) {
            const int k = pass * 64 + kb;
            float4 v = *reinterpret_cast<const float4*>(&T[k * TCOLS + o * KDIM + n0]);
            bs[n0 + 0][k] = bf_trunc(v.x);
            bs[n0 + 1][k] = bf_trunc(v.y);
            bs[n0 + 2][k] = bf_trunc(v.z);
            bs[n0 + 3][k] = bf_trunc(v.w);
        }
    }
    __syncthreads();

    // GEMM: wave's m-tile rows = (mq*4+wave)*16 + l15. Zero barriers.
    const int mt = mq * 4 + wave;
    f32x4 acc = {0.f, 0.f, 0.f, 0.f};
    const float* xr = &x[(mt * 16 + l15) * INF + q * 8];
    #pragma unroll 8
    for (int ks = 0; ks < 32; ++ks) {
        const int k0 = ks * 32;
        short8 bfr = *reinterpret_cast<const short8*>(&bs[l15][k0 + q * 8]);
        float4 a0 = *reinterpret_cast<const float4*>(xr + k0);
        float4 a1 = *reinterpret_cast<const float4*>(xr + k0 + 4);
        union { unsigned u[4]; short8 s; } ua;
        ua.u[0] = pack_bf2(a0.x, a0.y); ua.u[1] = pack_bf2(a0.z, a0.w);
        ua.u[2] = pack_bf2(a1.x, a1.y); ua.u[3] = pack_bf2(a1.z, a1.w);
        acc = __builtin_amdgcn_mfma_f32_16x16x32_bf16(ua.s, bfr, acc, 0, 0, 0);
    }

    // D layout (m89/m91): col(=kd)=l15, row(=b within tile)=q*4+r
    #pragma unroll
    for (int r = 0; r < 4; ++r)
        pmout[wave * 16 + q * 4 + r][l15] = __float2half(acc[r]);
    __syncthreads();

    // coalesced copy-out: 64 rows x 32 B -> mh[o][mq*64 + row][*]
    if (tid < 128) {
        const int row = tid >> 1, hh = tid & 1;
        uint4 v = *reinterpret_cast<const uint4*>(&pmout[row][hh * 8]);
        *reinterpret_cast<uint4*>(&mh[o * (BATCH * KDIM) + (mq * 64 + row) * KDIM + hh * 8]) = v;
    }
}

// ---------------------------------------------------------------- k_pair
// Block = (o, h), 1024 thr. mh[o] slice is contiguous 8 KB -> LDS, then R7's
// phase-B: i1 = tid&127 -> b1 = h*128+i1; bsel = tid>>7 -> b2 in [bsel*32,+32).
__global__ __launch_bounds__(1024) void k_pair(const float* __restrict__ x,
                                               const __half* __restrict__ mh,
                                               float* __restrict__ out) {
    const int blk = blockIdx.x;
    const int o   = blk & 127;
    const int h   = blk >> 7;
    const int tid = threadIdx.x;

    __shared__ __half2 pm[BATCH][8];    // 8 KB
    __shared__ float part[1024];        // 4 KB

    // prologue: copy x row blk into out (cols 0..1023)
    if (tid < 256)
        reinterpret_cast<float4*>(out)[blk * 288 + tid] =
            reinterpret_cast<const float4*>(x)[blk * 256 + tid];

    // load m-slice: 8 KB contiguous, 512 x uint4
    if (tid < 512) {
        uint4 v = *reinterpret_cast<const uint4*>(
            &mh[o * (BATCH * KDIM) + (tid >> 1) * KDIM + (tid & 1) * 8]);
        *reinterpret_cast<uint4*>(&pm[tid >> 1][(tid & 1) * 4]) = v;
    }
    __syncthreads();

    const int i1 = tid & 127;
    const int b1 = h * 128 + i1;
    const int bsel = tid >> 7;          // 0..7
    __half2 my[8];
    {
        union { uint4 u[2]; __half2 hh[8]; } c;
        c.u[0] = *reinterpret_cast<const uint4*>(&pm[b1][0]);
        c.u[1] = *reinterpret_cast<const uint4*>(&pm[b1][4]);
        #pragma unroll
        for (int j = 0; j < 8; ++j) my[j] = c.hh[j];
    }
    float tot = 0.f;
    const int b2_lo = bsel * 32;
    #pragma unroll 4
    for (int b2 = b2_lo; b2 < b2_lo + 32; ++b2) {
        union { uint4 u[2]; __half2 hh[8]; } co;     // wave-uniform -> broadcast
        co.u[0] = *reinterpret_cast<const uint4*>(&pm[b2][0]);
        co.u[1] = *reinterpret_cast<const uint4*>(&pm[b2][4]);
        __half2 e0 = __float2half2_rn(0.f), e1 = __float2half2_rn(0.f);
        __half2 e2 = __float2half2_rn(0.f), e3 = __float2half2_rn(0.f);
        #pragma unroll
        for (int j = 0; j < 2; ++j) {
            e0 = __hadd2(e0, __habs2(__hsub2(my[j],     co.hh[j])));
            e1 = __hadd2(e1, __habs2(__hsub2(my[j + 2], co.hh[j + 2])));
            e2 = __hadd2(e2, __habs2(__hsub2(my[j + 4], co.hh[j + 4])));
            e3 = __hadd2(e3, __habs2(__hsub2(my[j + 6], co.hh[j + 6])));
        }
        __half2 es = __hadd2(__hadd2(e0, e1), __hadd2(e2, e3));
        float n = __low2float(es) + __high2float(es);
        tot += __expf(-n);   // b2==b1: same LDS row -> diff bitwise 0 -> +1 exactly
    }
    part[bsel * 128 + i1] = tot;
    __syncthreads();

    // epilogue: combine 8 b2-eighths; -1 removes self-pair. One writer per (b,o).
    if (tid < 128) {
        float s = -1.0f;
        #pragma unroll
        for (int j = 0; j < 8; ++j) s += part[j * 128 + tid];
        out[(h * 128 + tid) * OCOLS + INF + o] = s;
    }
}

// ---------------------------------------------------------------- launch
extern "C" void kernel_launch(void* const* d_in, const int* in_sizes, int n_in,
                              void* d_out, int out_size, void* d_ws, size_t ws_size,
                              hipStream_t stream) {
    const float* x = (const float*)d_in[0];   // [256][1024]
    const float* T = (const float*)d_in[1];   // [1024][2048]
    float* out = (float*)d_out;               // [256][1152]
    __half* mh = (__half*)d_ws;               // [128][256][16] fp16 = 1 MB

    k_gemm<<<512, 256, 0, stream>>>(x, T, mh);
    k_pair<<<256, 1024, 0, stream>>>(x, mh, out);
}

// Round 9
// 87.886 us; speedup vs baseline: 1.8225x; 1.0073x over previous
//
#include <hip/hip_runtime.h>
#include <hip/hip_fp16.h>

// MinibatchDiscrimination  B=256, IN_F=1024, OUT_F=128, KD=16 (fp32 in/out)
// out[b] = concat(x[b], o_b[b]); o_b[b][o] = sum_b2 exp(-L1(m[b,o,:], m[b2,o,:])) - 1
//
// R9 (from R8's split, exec ~31 us = k_gemm ~18 + k_pair ~13):
//  - k_gemm: manual 4-stage register prefetch in the K-loop. R7 evidence:
//    VGPR_Count=32 -> compiler serialized the unroll-8 loads (needs 64 VGPRs
//    to batch them). Stages force 8 float4 in flight; __launch_bounds__(256,2)
//    grants the VGPR budget (cap 256) while keeping 2 blocks/CU.
//  - k_pair: 4 b1-rows per thread -> wave-uniform co read amortized 4x;
//    per-CU ds_read_b128 count 1024 -> 256 instr (~5.1 -> ~1.3 us); VALU
//    (~3.7 us) becomes the pair floor. 32 bsel x 8 b2 each.
// Numerics (R1-R8, absmax=0.0): cross-pair norms ~580 -> expf underflows to
// exact 0; self-pair diff bitwise 0 (same LDS row) -> +1 exactly, -1 at end.

#define BATCH 256
#define INF   1024
#define OUTF  128
#define KDIM  16
#define TCOLS 2048
#define OCOLS 1152
#define XB    1032   // bs row = 2064 B = 129*16: 16B-aligned, bank shift 4/row,
                     // b128 frag reads <=2-way aliased = free (m136)

typedef __attribute__((ext_vector_type(8))) short short8;
typedef __attribute__((ext_vector_type(4))) float f32x4;

// pack two fp32 -> two bf16 (trunc) in one v_perm: low16 = lo, high16 = hi
__device__ inline unsigned pack_bf2(float lo, float hi) {
    return __builtin_amdgcn_perm(__float_as_uint(hi), __float_as_uint(lo), 0x07060302u);
}
__device__ inline unsigned short bf_trunc(float f) {
    return (unsigned short)(__float_as_uint(f) >> 16);
}

// ---------------------------------------------------------------- k_gemm
// Block = (o 0..127, mq 0..3), 256 thr = 4 waves; wave w -> m-tile mq*4+w.
// B-slice staged once to LDS bf16; K-loop: A-frags from global x via 4-stage
// register prefetch (8 float4 outstanding), in-register fp32->bf16 cvt.
// 512 blocks = 2 blk/CU = 8 waves/CU.
__global__ __launch_bounds__(256, 2) void k_gemm(const float* __restrict__ x,
                                                 const float* __restrict__ T,
                                                 __half* __restrict__ mh) {
    const int blk = blockIdx.x;
    const int o   = blk & 127;
    const int mq  = blk >> 7;
    const int tid = threadIdx.x;
    const int wave = tid >> 6, lane = tid & 63;
    const int l15 = lane & 15, q = lane >> 4;

    __shared__ unsigned short bs[16][XB];   // 33,024 B
    __shared__ __half pmout[64][16];        //  2,048 B

    // stage B: bs[n][k] = bf16(T[k][o*16+n]); 16 passes x 64 k-rows (all
    // loads independent -> issue together, one drain)
    {
        const int kb = tid >> 2, n0 = (tid & 3) * 4;
        #pragma unroll
        for (int pass = 0; pass < 16; ++pass) {
            const int k = pass * 64 + kb;
            float4 v = *reinterpret_cast<const float4*>(&T[k * TCOLS + o * KDIM + n0]);
            bs[n0 + 0][k] = bf_trunc(v.x);
            bs[n0 + 1][k] = bf_trunc(v.y);
            bs[n0 + 2][k] = bf_trunc(v.z);
            bs[n0 + 3][k] = bf_trunc(v.w);
        }
    }
    __syncthreads();

    // K-loop with 4-stage register prefetch. A-frag: A[m=l15][k=q*8+j] (m89/m91).
    const int mt = mq * 4 + wave;
    const float* xr = &x[(mt * 16 + l15) * INF + q * 8];

    float4 st[4][2];
    #pragma unroll
    for (int p = 0; p < 4; ++p) {
        st[p][0] = *reinterpret_cast<const float4*>(xr + p * 32);
        st[p][1] = *reinterpret_cast<const float4*>(xr + p * 32 + 4);
    }
    f32x4 acc = {0.f, 0.f, 0.f, 0.f};
    #pragma unroll
    for (int ks = 0; ks < 32; ++ks) {
        const int p = ks & 3;
        float4 a0 = st[p][0], a1 = st[p][1];
        const int kn = (ks + 4 < 32) ? ks + 4 : ks;   // tail: dead reload, harmless
        st[p][0] = *reinterpret_cast<const float4*>(xr + kn * 32);
        st[p][1] = *reinterpret_cast<const float4*>(xr + kn * 32 + 4);
        short8 bfr = *reinterpret_cast<const short8*>(&bs[l15][ks * 32 + q * 8]);
        union { unsigned u[4]; short8 s; } ua;
        ua.u[0] = pack_bf2(a0.x, a0.y); ua.u[1] = pack_bf2(a0.z, a0.w);
        ua.u[2] = pack_bf2(a1.x, a1.y); ua.u[3] = pack_bf2(a1.z, a1.w);
        acc = __builtin_amdgcn_mfma_f32_16x16x32_bf16(ua.s, bfr, acc, 0, 0, 0);
    }

    // D layout (m89/m91): col(=kd)=l15, row(=b in tile)=q*4+r
    #pragma unroll
    for (int r = 0; r < 4; ++r)
        pmout[wave * 16 + q * 4 + r][l15] = __float2half(acc[r]);
    __syncthreads();

    // coalesced copy-out -> mh[o][mq*64 + row][*]  (pairwise-native layout)
    if (tid < 128) {
        const int row = tid >> 1, hh = tid & 1;
        uint4 v = *reinterpret_cast<const uint4*>(&pmout[row][hh * 8]);
        *reinterpret_cast<uint4*>(&mh[o * (BATCH * KDIM) + (mq * 64 + row) * KDIM + hh * 8]) = v;
    }
}

// ---------------------------------------------------------------- k_pair
// Block = (o, h), 1024 thr. Thread: i1 = tid&31, bsel = tid>>5 (0..31);
// owns 4 b1-rows {h*128 + r*32 + i1} vs b2 in [bsel*8, bsel*8+8).
// co read (wave-uniform broadcast) amortized over 4 rows.
__global__ __launch_bounds__(1024) void k_pair(const float* __restrict__ x,
                                               const __half* __restrict__ mh,
                                               float* __restrict__ out) {
    const int blk = blockIdx.x;
    const int o   = blk & 127;
    const int h   = blk >> 7;
    const int tid = threadIdx.x;

    __shared__ __half2 pm[BATCH][8];      //  8 KB
    __shared__ float part[32][128];       // 16 KB  [bsel][b1-local]

    // prologue: copy x row blk into out (cols 0..1023)
    if (tid < 256)
        reinterpret_cast<float4*>(out)[blk * 288 + tid] =
            reinterpret_cast<const float4*>(x)[blk * 256 + tid];

    // load m-slice: contiguous 8 KB, 512 x uint4
    if (tid < 512) {
        uint4 v = *reinterpret_cast<const uint4*>(
            &mh[o * (BATCH * KDIM) + (tid >> 1) * KDIM + (tid & 1) * 8]);
        *reinterpret_cast<uint4*>(&pm[tid >> 1][(tid & 1) * 4]) = v;
    }
    __syncthreads();

    const int i1 = tid & 31;
    const int bsel = tid >> 5;            // 0..31
    __half2 my[4][8];
    #pragma unroll
    for (int r = 0; r < 4; ++r) {
        union { uint4 u[2]; __half2 hh[8]; } c;
        c.u[0] = *reinterpret_cast<const uint4*>(&pm[h * 128 + r * 32 + i1][0]);
        c.u[1] = *reinterpret_cast<const uint4*>(&pm[h * 128 + r * 32 + i1][4]);
        #pragma unroll
        for (int j = 0; j < 8; ++j) my[r][j] = c.hh[j];
    }

    float tot[4] = {0.f, 0.f, 0.f, 0.f};
    const int b2_lo = bsel * 8;
    #pragma unroll
    for (int b2 = b2_lo; b2 < b2_lo + 8; ++b2) {
        union { uint4 u[2]; __half2 hh[8]; } co;      // wave-uniform -> broadcast
        co.u[0] = *reinterpret_cast<const uint4*>(&pm[b2][0]);
        co.u[1] = *reinterpret_cast<const uint4*>(&pm[b2][4]);
        #pragma unroll
        for (int r = 0; r < 4; ++r) {
            __half2 e0 = __habs2(__hsub2(my[r][0], co.hh[0]));
            __half2 e1 = __habs2(__hsub2(my[r][1], co.hh[1]));
            __half2 e2 = __habs2(__hsub2(my[r][2], co.hh[2]));
            __half2 e3 = __habs2(__hsub2(my[r][3], co.hh[3]));
            e0 = __hadd2(e0, __habs2(__hsub2(my[r][4], co.hh[4])));
            e1 = __hadd2(e1, __habs2(__hsub2(my[r][5], co.hh[5])));
            e2 = __hadd2(e2, __habs2(__hsub2(my[r][6], co.hh[6])));
            e3 = __hadd2(e3, __habs2(__hsub2(my[r][7], co.hh[7])));
            __half2 es = __hadd2(__hadd2(e0, e1), __hadd2(e2, e3));
            float n = __low2float(es) + __high2float(es);
            tot[r] += __expf(-n);   // b2==b1: same pm row -> diff bitwise 0 -> +1 exact
        }
    }
    #pragma unroll
    for (int r = 0; r < 4; ++r)
        part[bsel][r * 32 + i1] = tot[r];
    __syncthreads();

    // epilogue: sum 32 bsel partials; -1 removes self-pair. One writer per (b,o).
    if (tid < 128) {
        float s = -1.0f;
        #pragma unroll
        for (int j = 0; j < 32; ++j) s += part[j][tid];
        out[(h * 128 + tid) * OCOLS + INF + o] = s;
    }
}

// ---------------------------------------------------------------- launch
extern "C" void kernel_launch(void* const* d_in, const int* in_sizes, int n_in,
                              void* d_out, int out_size, void* d_ws, size_t ws_size,
                              hipStream_t stream) {
    const float* x = (const float*)d_in[0];   // [256][1024]
    const float* T = (const float*)d_in[1];   // [1024][2048]
    float* out = (float*)d_out;               // [256][1152]
    __half* mh = (__half*)d_ws;               // [128][256][16] fp16 = 1 MB

    k_gemm<<<512, 256, 0, stream>>>(x, T, mh);
    k_pair<<<256, 1024, 0, stream>>>(x, mh, out);
}